// Round 10
// baseline (576.429 us; speedup 1.0000x reference)
//
#include <hip/hip_runtime.h>
#include <hip/hip_bf16.h>
#include <cstdint>
#include <cstddef>

// Problem constants (from reference)
#define NBAGS  16
#define NNODES 5000
#define NEDGES 160000
#define DIN    128
#define DENC   256   // == D_GNN
#define DFC    128
#define NCLS   2

#define TPB 40       // row-tiles of 128 per bag (40*128 = 5120 >= 5000)
#define HB  32       // hist blocks per bag
#define HEPB (NEDGES / HB)   // 5000 edges per hist block

typedef __attribute__((ext_vector_type(8))) short short8;
typedef __attribute__((ext_vector_type(4))) float f32x4;

static __device__ __forceinline__ ushort f2b(float v) {
    __hip_bfloat16 b = __float2bfloat16(v);   // RNE
    return *reinterpret_cast<ushort*>(&b);
}

// ---------------------------------------------------------------------------
// bf16 MFMA GEMM, bag-pinned grid: 16 bags x 40 row-tiles x 2 col-halves =
// 1280 blocks; bag = blockIdx&15 -> XCD bag%8 (same mapping as agg/cvt).
// C[5000 x 256] per bag = act( A1@W1t^T (+ A2@W2t^T) + bias ), bf16 out.
// REDUCE=true: column-sum relu() into emb[bag][col] (g2 never materialized).
// BM=128, BN=128, BK=32; 4 waves, 4x4 mfma_f32_16x16x32_bf16 each.
// ---------------------------------------------------------------------------
template<bool DUAL, bool RELU, bool REDUCE>
__global__ __launch_bounds__(256)
void gemm_bf16_kernel(const ushort* __restrict__ A1, const ushort* __restrict__ Wt1,
                      const ushort* __restrict__ A2, const ushort* __restrict__ Wt2,
                      const float* __restrict__ bias, ushort* __restrict__ C,
                      float* __restrict__ emb, int K)
{
    constexpr int LDSP = 40;
    __shared__ __align__(16) ushort As[128 * LDSP];
    __shared__ __align__(16) ushort Bs[128 * LDSP];

    const int bx   = blockIdx.x;
    const int bag  = bx & 15;
    const int rem  = bx >> 4;          // 0..79
    const int col  = rem & 1;
    const int tile = rem >> 1;         // 0..39
    const size_t bagRow0 = (size_t)bag * NNODES;
    const int rloc0 = tile * 128;
    const int n0 = col * 128;

    const int tid  = threadIdx.x;
    const int wave = tid >> 6;
    const int lane = tid & 63;
    const int quad = lane >> 4;
    const int l16  = lane & 15;
    const int wm   = (wave >> 1) * 64;
    const int wn   = (wave & 1) * 64;

    f32x4 acc[4][4];
#pragma unroll
    for (int i = 0; i < 4; ++i)
#pragma unroll
        for (int j = 0; j < 4; ++j)
#pragma unroll
            for (int r = 0; r < 4; ++r) acc[i][j][r] = 0.f;

    const int sr = tid >> 1;           // staging row 0..127
    const int sk = (tid & 1) * 16;

    const int npass = DUAL ? 2 : 1;
    for (int pass = 0; pass < npass; ++pass) {
        const ushort* __restrict__ A = (DUAL && pass) ? A2 : A1;
        const ushort* __restrict__ W = (DUAL && pass) ? Wt2 : Wt1;

        for (int k0 = 0; k0 < K; k0 += 32) {
            {
                uint4 v0 = make_uint4(0, 0, 0, 0), v1 = make_uint4(0, 0, 0, 0);
                const int rl = rloc0 + sr;
                if (rl < NNODES) {
                    const uint4* src = (const uint4*)(A + (bagRow0 + rl) * K + k0 + sk);
                    v0 = src[0]; v1 = src[1];
                }
                *(uint4*)&As[sr * LDSP + sk]     = v0;
                *(uint4*)&As[sr * LDSP + sk + 8] = v1;
            }
            {
                const uint4* src = (const uint4*)(W + (size_t)(n0 + sr) * K + k0 + sk);
                *(uint4*)&Bs[sr * LDSP + sk]     = src[0];
                *(uint4*)&Bs[sr * LDSP + sk + 8] = src[1];
            }
            __syncthreads();

            short8 af[4], bf[4];
#pragma unroll
            for (int t = 0; t < 4; ++t) {
                af[t] = *(const short8*)&As[(wm + t * 16 + l16) * LDSP + quad * 8];
                bf[t] = *(const short8*)&Bs[(wn + t * 16 + l16) * LDSP + quad * 8];
            }
#pragma unroll
            for (int tm = 0; tm < 4; ++tm)
#pragma unroll
                for (int tn = 0; tn < 4; ++tn)
                    acc[tm][tn] = __builtin_amdgcn_mfma_f32_16x16x32_bf16(
                        af[tm], bf[tn], acc[tm][tn], 0, 0, 0);
            __syncthreads();
        }
    }

    if (!REDUCE) {
        // epilogue: bias + relu, bf16 store. C/D: row = quad*4+reg, col = l16
#pragma unroll
        for (int tm = 0; tm < 4; ++tm) {
            const int rbase = rloc0 + wm + tm * 16 + quad * 4;
#pragma unroll
            for (int reg = 0; reg < 4; ++reg) {
                const int rl = rbase + reg;
                if (rl < NNODES) {
#pragma unroll
                    for (int tn = 0; tn < 4; ++tn) {
                        const int gcol = n0 + wn + tn * 16 + l16;
                        float v = acc[tm][tn][reg] + bias[gcol];
                        if (RELU) v = fmaxf(v, 0.f);
                        C[(bagRow0 + rl) * 256 + gcol] = f2b(v);
                    }
                }
            }
        }
    } else {
        // fused column-sum epilogue -> emb[bag] (single bag per block)
        __shared__ float red[128];
        if (tid < 128) red[tid] = 0.f;
        __syncthreads();
#pragma unroll
        for (int tn = 0; tn < 4; ++tn) {
            const int cl = wn + tn * 16 + l16;            // 0..127
            const float bv = bias[n0 + cl];
            float p = 0.f;
#pragma unroll
            for (int tm = 0; tm < 4; ++tm) {
#pragma unroll
                for (int reg = 0; reg < 4; ++reg) {
                    const int rl = rloc0 + wm + tm * 16 + quad * 4 + reg;
                    float v = acc[tm][tn][reg] + bv;
                    if (RELU) v = fmaxf(v, 0.f);
                    if (rl < NNODES) p += v;
                }
            }
            atomicAdd(&red[cl], p);
        }
        __syncthreads();
        if (tid < 128)
            atomicAdd(&emb[bag * DENC + n0 + tid], red[tid]);
    }
}

// ---------------------------------------------------------------------------
// Weight convert+transpose: Wt[n*K+k] = bf16(W[k*256+n])
// ---------------------------------------------------------------------------
__global__ __launch_bounds__(256)
void wt_transpose_kernel(const float* __restrict__ W, ushort* __restrict__ Wt, int K)
{
    const int idx = blockIdx.x * 256 + threadIdx.x;
    if (idx < 256 * K) {
        const int n = idx / K;
        const int k = idx - n * K;
        Wt[idx] = f2b(W[k * 256 + n]);
    }
}

// x (fp32) -> bf16, bag-pinned (bag = bx&15). grid = 16*625, 4 elems/thread.
__global__ __launch_bounds__(256)
void cvt_bf16_kernel(const float* __restrict__ x, ushort* __restrict__ xb)
{
    const int bag = blockIdx.x & 15;
    const int chunk = blockIdx.x >> 4;
    const size_t base = (size_t)bag * (NNODES * DIN / 4);
    const int i = chunk * 256 + threadIdx.x;
    const float4 v = ((const float4*)x)[base + i];
    ushort4 o;
    o.x = f2b(v.x); o.y = f2b(v.y); o.z = f2b(v.z); o.w = f2b(v.w);
    ((ushort4*)xb)[base + i] = o;
}

// ---------------------------------------------------------------------------
// Atomic-free CSR build (counting sort with LDS histograms).
//   hist : per (bag,blk): LDS-histogram 5000 edges -> histG[bag][blk][*]
//   scan : per bag: rowptr = scan; rewrite histG as per-(blk,node) offsets
//   place: per (bag,blk): offsets -> LDS, pos = LDS-atomicAdd, scatter u16
// ---------------------------------------------------------------------------
__global__ __launch_bounds__(256)
void hist_kernel(const int* __restrict__ edges, int* __restrict__ histG)
{
    const int bag = blockIdx.x & 15;
    const int blk = blockIdx.x >> 4;
    __shared__ int h[NNODES];
    for (int i = threadIdx.x; i < NNODES; i += 256) h[i] = 0;
    __syncthreads();
    const int* __restrict__ dstp = edges + (size_t)bag * 2 * NEDGES + NEDGES + blk * HEPB;
    for (int r = threadIdx.x; r < HEPB; r += 256)
        atomicAdd(&h[__builtin_nontemporal_load(&dstp[r])], 1);
    __syncthreads();
    int* __restrict__ out = histG + ((size_t)bag * HB + blk) * NNODES;
    for (int i = threadIdx.x; i < NNODES; i += 256) out[i] = h[i];
}

__global__ __launch_bounds__(1024)
void scan_kernel(int* __restrict__ histG, int* __restrict__ rowptr)
{
    const int b = blockIdx.x;
    const int t = threadIdx.x;
    __shared__ int sh[1024];
    const int CH = 5;                    // 1024*5 >= 5000
    const int base = t * CH;
    int* __restrict__ hb = histG + (size_t)b * HB * NNODES;
    int local[CH];
    int sum = 0;
#pragma unroll
    for (int i = 0; i < CH; ++i) {
        const int g = base + i;
        int s = 0;
        if (g < NNODES)
            for (int blk = 0; blk < HB; ++blk) s += hb[blk * NNODES + g];
        local[i] = s; sum += s;
    }
    sh[t] = sum;
    __syncthreads();
    for (int off = 1; off < 1024; off <<= 1) {
        const int add = (t >= off) ? sh[t - off] : 0;
        __syncthreads();
        sh[t] += add;
        __syncthreads();
    }
    int run = sh[t] - sum;               // exclusive prefix over nodes
#pragma unroll
    for (int i = 0; i < CH; ++i) {
        const int g = base + i;
        if (g < NNODES) {
            rowptr[b * (NNODES + 1) + g] = run;
            int off = run;
            for (int blk = 0; blk < HB; ++blk) {
                int* p = &hb[blk * NNODES + g];
                const int v = *p;
                *p = off;                // per-(blk,node) start offset
                off += v;
            }
        }
        run += local[i];
    }
    if (t == 1023) rowptr[b * (NNODES + 1) + NNODES] = run;  // == NEDGES
}

__global__ __launch_bounds__(256)
void place_kernel(const int* __restrict__ edges, const int* __restrict__ histG,
                  ushort* __restrict__ colidx)
{
    const int bag = blockIdx.x & 15;
    const int blk = blockIdx.x >> 4;
    __shared__ int h[NNODES];
    const int* __restrict__ offs = histG + ((size_t)bag * HB + blk) * NNODES;
    for (int i = threadIdx.x; i < NNODES; i += 256) h[i] = offs[i];
    __syncthreads();
    const int* __restrict__ eb = edges + (size_t)bag * 2 * NEDGES;
    ushort* __restrict__ co = colidx + (size_t)bag * NEDGES;
    const int e0 = blk * HEPB;
    for (int r = threadIdx.x; r < HEPB; r += 256) {
        const int s = __builtin_nontemporal_load(&eb[e0 + r]);
        const int d = __builtin_nontemporal_load(&eb[NEDGES + e0 + r]);
        const int pos = atomicAdd(&h[d], 1);     // LDS atomic, CU-local
        co[pos] = (ushort)s;
    }
}

// ---------------------------------------------------------------------------
// Mean aggregation (pull), bf16 in/out, fp32 accumulate.
// One WAVE per node: 64 lanes x 8 B = one feature row per vmem instr.
// Launched in TWO batches of 8 bags (bag = base + bx&7): one bag per XCD, so
// the 2.56 MB gather source + 0.32 MB colidx fit the 4 MB XCD L2 — every
// reuse (avg deg 32) is an L2 hit. Output written non-temporally (as u64)
// so the 2.56 MB write stream doesn't evict the gather source.
// ---------------------------------------------------------------------------
__global__ __launch_bounds__(256)
void agg_mean_kernel(const ushort* __restrict__ X, const int* __restrict__ rowptr,
                     const ushort* __restrict__ colidx, ushort* __restrict__ M,
                     int batchBase)
{
    const int bx = blockIdx.x;
    const int bag = batchBase + (bx & 7);
    const int grp = bx >> 3;                  // 0..1249
    const int wave = threadIdx.x >> 6;
    const int lane = threadIdx.x & 63;
    const int node = grp * 4 + wave;

    const int* rp = rowptr + bag * (NNODES + 1);
    const int s = rp[node];
    const int e = rp[node + 1];
    const float inv = 1.0f / fmaxf((float)(e - s), 1.0f);
    const uint2* __restrict__ Xb = (const uint2*)(X + (size_t)bag * NNODES * DENC);
    const ushort* __restrict__ ci = colidx + (size_t)bag * NEDGES;

    float2 p0 = {0.f, 0.f}, p1 = {0.f, 0.f};
    int j = s;
    for (; j + 4 <= e; j += 4) {
        const int i0 = ci[j], i1 = ci[j + 1], i2 = ci[j + 2], i3 = ci[j + 3];
        const uint2 u0 = Xb[i0 * 64 + lane];
        const uint2 u1 = Xb[i1 * 64 + lane];
        const uint2 u2 = Xb[i2 * 64 + lane];
        const uint2 u3 = Xb[i3 * 64 + lane];
        p0.x += __uint_as_float(u0.x << 16); p0.y += __uint_as_float(u0.x & 0xffff0000u);
        p1.x += __uint_as_float(u0.y << 16); p1.y += __uint_as_float(u0.y & 0xffff0000u);
        p0.x += __uint_as_float(u1.x << 16); p0.y += __uint_as_float(u1.x & 0xffff0000u);
        p1.x += __uint_as_float(u1.y << 16); p1.y += __uint_as_float(u1.y & 0xffff0000u);
        p0.x += __uint_as_float(u2.x << 16); p0.y += __uint_as_float(u2.x & 0xffff0000u);
        p1.x += __uint_as_float(u2.y << 16); p1.y += __uint_as_float(u2.y & 0xffff0000u);
        p0.x += __uint_as_float(u3.x << 16); p0.y += __uint_as_float(u3.x & 0xffff0000u);
        p1.x += __uint_as_float(u3.y << 16); p1.y += __uint_as_float(u3.y & 0xffff0000u);
    }
    for (; j < e; ++j) {
        const uint2 u = Xb[ci[j] * 64 + lane];
        p0.x += __uint_as_float(u.x << 16); p0.y += __uint_as_float(u.x & 0xffff0000u);
        p1.x += __uint_as_float(u.y << 16); p1.y += __uint_as_float(u.y & 0xffff0000u);
    }
    const uint32_t w0 = (uint32_t)f2b(p0.x * inv) | ((uint32_t)f2b(p0.y * inv) << 16);
    const uint32_t w1 = (uint32_t)f2b(p1.x * inv) | ((uint32_t)f2b(p1.y * inv) << 16);
    const uint64_t o = (uint64_t)w0 | ((uint64_t)w1 << 32);
    uint64_t* dst = (uint64_t*)(M + ((size_t)bag * NNODES + node) * DENC) + lane;
    __builtin_nontemporal_store(o, dst);
}

// ---------------------------------------------------------------------------
// classifier (fp32): out[b] = relu(emb[b]@Wc1 + bc1) @ Wc2 + bc2
// ---------------------------------------------------------------------------
__global__ __launch_bounds__(128)
void classifier_kernel(const float* __restrict__ emb, const float* __restrict__ Wc1,
                       const float* __restrict__ bc1, const float* __restrict__ Wc2,
                       const float* __restrict__ bc2, float* __restrict__ out)
{
    const int b = blockIdx.x;
    const int t = threadIdx.x;  // 128
    __shared__ float se[DENC];
    se[t] = emb[b * DENC + t];
    se[128 + t] = emb[b * DENC + 128 + t];
    __syncthreads();
    float h = bc1[t];
    for (int k = 0; k < DENC; ++k) h = fmaf(se[k], Wc1[k * DFC + t], h);
    h = fmaxf(h, 0.f);
    __shared__ float s0[128], s1[128];
    s0[t] = h * Wc2[t * NCLS + 0];
    s1[t] = h * Wc2[t * NCLS + 1];
    __syncthreads();
    for (int off = 64; off > 0; off >>= 1) {
        if (t < off) { s0[t] += s0[t + off]; s1[t] += s1[t + off]; }
        __syncthreads();
    }
    if (t == 0) {
        out[b * NCLS + 0] = s0[0] + bc2[0];
        out[b * NCLS + 1] = s1[0] + bc2[1];
    }
}

// ---------------------------------------------------------------------------
extern "C" void kernel_launch(void* const* d_in, const int* in_sizes, int n_in,
                              void* d_out, int out_size, void* d_ws, size_t ws_size,
                              hipStream_t stream)
{
    const float* x    = (const float*)d_in[0];
    const int*   edges= (const int*)d_in[1];   // int32 on device
    const float* We   = (const float*)d_in[2];
    const float* be   = (const float*)d_in[3];
    const float* Wl1  = (const float*)d_in[4];
    const float* bl1  = (const float*)d_in[5];
    const float* Wr1  = (const float*)d_in[6];
    const float* Wl2  = (const float*)d_in[7];
    const float* bl2  = (const float*)d_in[8];
    const float* Wr2  = (const float*)d_in[9];
    // d_in[10..12] = Wlp, blp, Wrp: dead (softmax over 1 cluster == 1)
    const float* Wc1  = (const float*)d_in[13];
    const float* bc1  = (const float*)d_in[14];
    const float* Wc2  = (const float*)d_in[15];
    const float* bc2  = (const float*)d_in[16];
    float* out = (float*)d_out;

    auto rnd = [](size_t v) { return (v + 255) & ~(size_t)255; };
    char* p = (char*)d_ws;
    auto alloc = [&](size_t bytes) -> char* {
        char* r = p; p += rnd(bytes); return r;
    };
    ushort* xb    = (ushort*)alloc((size_t)NBAGS * NNODES * DIN * 2);
    ushort* H     = (ushort*)alloc((size_t)NBAGS * NNODES * DENC * 2);  // h, then mean2
    ushort* Mb    = (ushort*)alloc((size_t)NBAGS * NNODES * DENC * 2);  // mean1
    ushort* Gb    = (ushort*)alloc((size_t)NBAGS * NNODES * DENC * 2);  // g1
    ushort* Wet   = (ushort*)alloc((size_t)256 * DIN * 2);
    ushort* Wl1t  = (ushort*)alloc((size_t)256 * DENC * 2);
    ushort* Wr1t  = (ushort*)alloc((size_t)256 * DENC * 2);
    ushort* Wl2t  = (ushort*)alloc((size_t)256 * DENC * 2);
    ushort* Wr2t  = (ushort*)alloc((size_t)256 * DENC * 2);
    int*    rowptr= (int*)   alloc((size_t)NBAGS * (NNODES + 1) * 4);
    int*    histG = (int*)   alloc((size_t)NBAGS * HB * NNODES * 4);   // 10.24 MB
    ushort* colidx= (ushort*)alloc((size_t)NBAGS * NEDGES * 2);
    float*  emb   = (float*) alloc((size_t)NBAGS * DENC * 4);

    // per-launch init (ws re-poisoned each call)
    (void)hipMemsetAsync(emb, 0, (size_t)NBAGS * DENC * 4, stream);

    // conversions
    cvt_bf16_kernel<<<NBAGS * 625, 256, 0, stream>>>(x, xb);
    wt_transpose_kernel<<<(256 * DIN + 255) / 256, 256, 0, stream>>>(We, Wet, DIN);
    wt_transpose_kernel<<<(256 * DENC + 255) / 256, 256, 0, stream>>>(Wl1, Wl1t, DENC);
    wt_transpose_kernel<<<(256 * DENC + 255) / 256, 256, 0, stream>>>(Wr1, Wr1t, DENC);
    wt_transpose_kernel<<<(256 * DENC + 255) / 256, 256, 0, stream>>>(Wl2, Wl2t, DENC);
    wt_transpose_kernel<<<(256 * DENC + 255) / 256, 256, 0, stream>>>(Wr2, Wr2t, DENC);

    // CSR build (atomic-free counting sort)
    hist_kernel<<<NBAGS * HB, 256, 0, stream>>>(edges, histG);
    scan_kernel<<<NBAGS, 1024, 0, stream>>>(histG, rowptr);
    place_kernel<<<NBAGS * HB, 256, 0, stream>>>(edges, histG, colidx);

    const int gemm_grid = NBAGS * TPB * 2;     // 1280
    const int agg_grid  = 8 * (NNODES / 4);    // 8 bags per launch

    // encoder: H = relu(x @ We + be)
    gemm_bf16_kernel<false, true, false><<<gemm_grid, 256, 0, stream>>>(
        xb, Wet, nullptr, nullptr, be, H, nullptr, DIN);

    // layer 1: g1 = relu(mean1@Wl1 + h@Wr1 + bl1)
    agg_mean_kernel<<<agg_grid, 256, 0, stream>>>(H, rowptr, colidx, Mb, 0);
    agg_mean_kernel<<<agg_grid, 256, 0, stream>>>(H, rowptr, colidx, Mb, 8);
    gemm_bf16_kernel<true, true, false><<<gemm_grid, 256, 0, stream>>>(
        Mb, Wl1t, H, Wr1t, bl1, Gb, nullptr, DENC);

    // layer 2 fused with emb reduction: emb += relu(mean2@Wl2 + g1@Wr2 + bl2)
    agg_mean_kernel<<<agg_grid, 256, 0, stream>>>(Gb, rowptr, colidx, H, 0);
    agg_mean_kernel<<<agg_grid, 256, 0, stream>>>(Gb, rowptr, colidx, H, 8);
    gemm_bf16_kernel<true, true, true><<<gemm_grid, 256, 0, stream>>>(
        H, Wl2t, Gb, Wr2t, bl2, nullptr, emb, DENC);

    classifier_kernel<<<NBAGS, 128, 0, stream>>>(emb, Wc1, bc1, Wc2, bc2, out);
}

// Round 11
// 513.808 us; speedup vs baseline: 1.1219x; 1.1219x over previous
//
#include <hip/hip_runtime.h>
#include <hip/hip_bf16.h>
#include <cstdint>
#include <cstddef>

// Problem constants (from reference)
#define NBAGS  16
#define NNODES 5000
#define NEDGES 160000
#define DIN    128
#define DENC   256   // == D_GNN
#define DFC    128
#define NCLS   2

#define TPB 40       // row-tiles of 128 per bag (40*128 = 5120 >= 5000)
#define HB  32       // hist blocks per bag
#define HEPB (NEDGES / HB)   // 5000 edges per hist block

typedef __attribute__((ext_vector_type(8))) short short8;
typedef __attribute__((ext_vector_type(4))) float f32x4;

static __device__ __forceinline__ ushort f2b(float v) {
    __hip_bfloat16 b = __float2bfloat16(v);   // RNE
    return *reinterpret_cast<ushort*>(&b);
}

// ---------------------------------------------------------------------------
// bf16 MFMA GEMM, bag-pinned grid: 16 bags x 40 row-tiles x 2 col-halves =
// 1280 blocks; bag = blockIdx&15 -> XCD bag%8 (same mapping as agg/cvt).
// C[5000 x 256] per bag = act( A1@W1t^T (+ A2@W2t^T) + bias ), bf16 out.
// REDUCE=true: column-sum relu() into emb[bag][col] (g2 never materialized).
// BM=128, BN=128, BK=32; 4 waves, 4x4 mfma_f32_16x16x32_bf16 each.
// ---------------------------------------------------------------------------
template<bool DUAL, bool RELU, bool REDUCE>
__global__ __launch_bounds__(256)
void gemm_bf16_kernel(const ushort* __restrict__ A1, const ushort* __restrict__ Wt1,
                      const ushort* __restrict__ A2, const ushort* __restrict__ Wt2,
                      const float* __restrict__ bias, ushort* __restrict__ C,
                      float* __restrict__ emb, int K)
{
    constexpr int LDSP = 40;
    __shared__ __align__(16) ushort As[128 * LDSP];
    __shared__ __align__(16) ushort Bs[128 * LDSP];

    const int bx   = blockIdx.x;
    const int bag  = bx & 15;
    const int rem  = bx >> 4;          // 0..79
    const int col  = rem & 1;
    const int tile = rem >> 1;         // 0..39
    const size_t bagRow0 = (size_t)bag * NNODES;
    const int rloc0 = tile * 128;
    const int n0 = col * 128;

    const int tid  = threadIdx.x;
    const int wave = tid >> 6;
    const int lane = tid & 63;
    const int quad = lane >> 4;
    const int l16  = lane & 15;
    const int wm   = (wave >> 1) * 64;
    const int wn   = (wave & 1) * 64;

    f32x4 acc[4][4];
#pragma unroll
    for (int i = 0; i < 4; ++i)
#pragma unroll
        for (int j = 0; j < 4; ++j)
#pragma unroll
            for (int r = 0; r < 4; ++r) acc[i][j][r] = 0.f;

    const int sr = tid >> 1;           // staging row 0..127
    const int sk = (tid & 1) * 16;

    const int npass = DUAL ? 2 : 1;
    for (int pass = 0; pass < npass; ++pass) {
        const ushort* __restrict__ A = (DUAL && pass) ? A2 : A1;
        const ushort* __restrict__ W = (DUAL && pass) ? Wt2 : Wt1;

        for (int k0 = 0; k0 < K; k0 += 32) {
            {
                uint4 v0 = make_uint4(0, 0, 0, 0), v1 = make_uint4(0, 0, 0, 0);
                const int rl = rloc0 + sr;
                if (rl < NNODES) {
                    const uint4* src = (const uint4*)(A + (bagRow0 + rl) * K + k0 + sk);
                    v0 = src[0]; v1 = src[1];
                }
                *(uint4*)&As[sr * LDSP + sk]     = v0;
                *(uint4*)&As[sr * LDSP + sk + 8] = v1;
            }
            {
                const uint4* src = (const uint4*)(W + (size_t)(n0 + sr) * K + k0 + sk);
                *(uint4*)&Bs[sr * LDSP + sk]     = src[0];
                *(uint4*)&Bs[sr * LDSP + sk + 8] = src[1];
            }
            __syncthreads();

            short8 af[4], bf[4];
#pragma unroll
            for (int t = 0; t < 4; ++t) {
                af[t] = *(const short8*)&As[(wm + t * 16 + l16) * LDSP + quad * 8];
                bf[t] = *(const short8*)&Bs[(wn + t * 16 + l16) * LDSP + quad * 8];
            }
#pragma unroll
            for (int tm = 0; tm < 4; ++tm)
#pragma unroll
                for (int tn = 0; tn < 4; ++tn)
                    acc[tm][tn] = __builtin_amdgcn_mfma_f32_16x16x32_bf16(
                        af[tm], bf[tn], acc[tm][tn], 0, 0, 0);
            __syncthreads();
        }
    }

    if (!REDUCE) {
        // epilogue: bias + relu, bf16 store. C/D: row = quad*4+reg, col = l16
#pragma unroll
        for (int tm = 0; tm < 4; ++tm) {
            const int rbase = rloc0 + wm + tm * 16 + quad * 4;
#pragma unroll
            for (int reg = 0; reg < 4; ++reg) {
                const int rl = rbase + reg;
                if (rl < NNODES) {
#pragma unroll
                    for (int tn = 0; tn < 4; ++tn) {
                        const int gcol = n0 + wn + tn * 16 + l16;
                        float v = acc[tm][tn][reg] + bias[gcol];
                        if (RELU) v = fmaxf(v, 0.f);
                        C[(bagRow0 + rl) * 256 + gcol] = f2b(v);
                    }
                }
            }
        }
    } else {
        // fused column-sum epilogue -> emb[bag] (single bag per block)
        __shared__ float red[128];
        if (tid < 128) red[tid] = 0.f;
        __syncthreads();
#pragma unroll
        for (int tn = 0; tn < 4; ++tn) {
            const int cl = wn + tn * 16 + l16;            // 0..127
            const float bv = bias[n0 + cl];
            float p = 0.f;
#pragma unroll
            for (int tm = 0; tm < 4; ++tm) {
#pragma unroll
                for (int reg = 0; reg < 4; ++reg) {
                    const int rl = rloc0 + wm + tm * 16 + quad * 4 + reg;
                    float v = acc[tm][tn][reg] + bv;
                    if (RELU) v = fmaxf(v, 0.f);
                    if (rl < NNODES) p += v;
                }
            }
            atomicAdd(&red[cl], p);
        }
        __syncthreads();
        if (tid < 128)
            atomicAdd(&emb[bag * DENC + n0 + tid], red[tid]);
    }
}

// ---------------------------------------------------------------------------
// Weight convert+transpose: Wt[n*K+k] = bf16(W[k*256+n])
// ---------------------------------------------------------------------------
__global__ __launch_bounds__(256)
void wt_transpose_kernel(const float* __restrict__ W, ushort* __restrict__ Wt, int K)
{
    const int idx = blockIdx.x * 256 + threadIdx.x;
    if (idx < 256 * K) {
        const int n = idx / K;
        const int k = idx - n * K;
        Wt[idx] = f2b(W[k * 256 + n]);
    }
}

// x (fp32) -> bf16, bag-pinned (bag = bx&15). grid = 16*625, 4 elems/thread.
__global__ __launch_bounds__(256)
void cvt_bf16_kernel(const float* __restrict__ x, ushort* __restrict__ xb)
{
    const int bag = blockIdx.x & 15;
    const int chunk = blockIdx.x >> 4;
    const size_t base = (size_t)bag * (NNODES * DIN / 4);
    const int i = chunk * 256 + threadIdx.x;
    const float4 v = ((const float4*)x)[base + i];
    ushort4 o;
    o.x = f2b(v.x); o.y = f2b(v.y); o.z = f2b(v.z); o.w = f2b(v.w);
    ((ushort4*)xb)[base + i] = o;
}

// ---------------------------------------------------------------------------
// Atomic-free CSR build (counting sort with LDS histograms).
//   hist   : per (bag,blk): LDS-histogram 5000 edges -> histG[bag][blk][*]
//   colsum : thread = node; walk the 32 block-counts coalesced, rewrite in
//            place as node-relative exclusive prefixes, total -> cnt
//   scan   : per bag: exclusive LDS scan of the 5000 cnt values -> rowptr
//   place  : per (bag,blk): h[i] = rowptr[i] + rel[i] in LDS,
//            pos = LDS-atomicAdd, scatter colidx u16
// (old single scan_kernel did colsum+scan with 16 blocks x 32-step serial
//  strided walks: 74 µs at 2% occupancy — split for parallelism)
// ---------------------------------------------------------------------------
__global__ __launch_bounds__(256)
void hist_kernel(const int* __restrict__ edges, int* __restrict__ histG)
{
    const int bag = blockIdx.x & 15;
    const int blk = blockIdx.x >> 4;
    __shared__ int h[NNODES];
    for (int i = threadIdx.x; i < NNODES; i += 256) h[i] = 0;
    __syncthreads();
    const int* __restrict__ dstp = edges + (size_t)bag * 2 * NEDGES + NEDGES + blk * HEPB;
    for (int r = threadIdx.x; r < HEPB; r += 256)
        atomicAdd(&h[__builtin_nontemporal_load(&dstp[r])], 1);
    __syncthreads();
    int* __restrict__ out = histG + ((size_t)bag * HB + blk) * NNODES;
    for (int i = threadIdx.x; i < NNODES; i += 256) out[i] = h[i];
}

// grid: 16 bags x 20 node-chunks of 256 (5120 >= 5000)
__global__ __launch_bounds__(256)
void colsum_kernel(int* __restrict__ histG, int* __restrict__ cnt)
{
    const int bag = blockIdx.x & 15;
    const int chunk = blockIdx.x >> 4;
    const int node = chunk * 256 + threadIdx.x;
    if (node >= NNODES) return;
    int* __restrict__ hb = histG + (size_t)bag * HB * NNODES + node;
    int run = 0;
#pragma unroll 8
    for (int blk = 0; blk < HB; ++blk) {
        int* p = hb + blk * NNODES;
        const int v = *p;
        *p = run;                        // node-relative exclusive prefix
        run += v;
    }
    cnt[bag * NNODES + node] = run;      // node degree
}

__global__ __launch_bounds__(1024)
void scan_kernel(const int* __restrict__ cnt, int* __restrict__ rowptr)
{
    const int b = blockIdx.x;
    const int t = threadIdx.x;
    __shared__ int sh[1024];
    const int CH = 5;                    // 1024*5 >= 5000
    const int base = t * CH;
    int local[CH];
    int sum = 0;
#pragma unroll
    for (int i = 0; i < CH; ++i) {
        const int g = base + i;
        const int v = (g < NNODES) ? cnt[b * NNODES + g] : 0;
        local[i] = v; sum += v;
    }
    sh[t] = sum;
    __syncthreads();
    for (int off = 1; off < 1024; off <<= 1) {
        const int add = (t >= off) ? sh[t - off] : 0;
        __syncthreads();
        sh[t] += add;
        __syncthreads();
    }
    int run = sh[t] - sum;               // exclusive prefix over nodes
#pragma unroll
    for (int i = 0; i < CH; ++i) {
        const int g = base + i;
        if (g < NNODES) rowptr[b * (NNODES + 1) + g] = run;
        run += local[i];
    }
    if (t == 1023) rowptr[b * (NNODES + 1) + NNODES] = run;  // == NEDGES
}

__global__ __launch_bounds__(256)
void place_kernel(const int* __restrict__ edges, const int* __restrict__ histG,
                  const int* __restrict__ rowptr, ushort* __restrict__ colidx)
{
    const int bag = blockIdx.x & 15;
    const int blk = blockIdx.x >> 4;
    __shared__ int h[NNODES];
    const int* __restrict__ rel = histG + ((size_t)bag * HB + blk) * NNODES;
    const int* __restrict__ rp  = rowptr + bag * (NNODES + 1);
    for (int i = threadIdx.x; i < NNODES; i += 256) h[i] = rp[i] + rel[i];
    __syncthreads();
    const int* __restrict__ eb = edges + (size_t)bag * 2 * NEDGES;
    ushort* __restrict__ co = colidx + (size_t)bag * NEDGES;
    const int e0 = blk * HEPB;
    for (int r = threadIdx.x; r < HEPB; r += 256) {
        const int s = __builtin_nontemporal_load(&eb[e0 + r]);
        const int d = __builtin_nontemporal_load(&eb[NEDGES + e0 + r]);
        const int pos = atomicAdd(&h[d], 1);     // LDS atomic, CU-local
        co[pos] = (ushort)s;
    }
}

// ---------------------------------------------------------------------------
// Mean aggregation (pull), bf16 in/out, fp32 accumulate.
// One WAVE per node: 64 lanes x 8 B = one feature row per vmem instr.
// Launched in TWO batches of 8 bags (bag = base + bx&7): one bag per XCD, so
// the 2.56 MB gather source + 0.32 MB colidx fit the 4 MB XCD L2 — every
// reuse (avg deg 32) is an L2 hit. Output written non-temporally (as u64)
// so the 2.56 MB write stream doesn't evict the gather source.
// ---------------------------------------------------------------------------
__global__ __launch_bounds__(256)
void agg_mean_kernel(const ushort* __restrict__ X, const int* __restrict__ rowptr,
                     const ushort* __restrict__ colidx, ushort* __restrict__ M,
                     int batchBase)
{
    const int bx = blockIdx.x;
    const int bag = batchBase + (bx & 7);
    const int grp = bx >> 3;                  // 0..1249
    const int wave = threadIdx.x >> 6;
    const int lane = threadIdx.x & 63;
    const int node = grp * 4 + wave;

    const int* rp = rowptr + bag * (NNODES + 1);
    const int s = rp[node];
    const int e = rp[node + 1];
    const float inv = 1.0f / fmaxf((float)(e - s), 1.0f);
    const uint2* __restrict__ Xb = (const uint2*)(X + (size_t)bag * NNODES * DENC);
    const ushort* __restrict__ ci = colidx + (size_t)bag * NEDGES;

    float2 p0 = {0.f, 0.f}, p1 = {0.f, 0.f};
    int j = s;
    for (; j + 4 <= e; j += 4) {
        const int i0 = ci[j], i1 = ci[j + 1], i2 = ci[j + 2], i3 = ci[j + 3];
        const uint2 u0 = Xb[i0 * 64 + lane];
        const uint2 u1 = Xb[i1 * 64 + lane];
        const uint2 u2 = Xb[i2 * 64 + lane];
        const uint2 u3 = Xb[i3 * 64 + lane];
        p0.x += __uint_as_float(u0.x << 16); p0.y += __uint_as_float(u0.x & 0xffff0000u);
        p1.x += __uint_as_float(u0.y << 16); p1.y += __uint_as_float(u0.y & 0xffff0000u);
        p0.x += __uint_as_float(u1.x << 16); p0.y += __uint_as_float(u1.x & 0xffff0000u);
        p1.x += __uint_as_float(u1.y << 16); p1.y += __uint_as_float(u1.y & 0xffff0000u);
        p0.x += __uint_as_float(u2.x << 16); p0.y += __uint_as_float(u2.x & 0xffff0000u);
        p1.x += __uint_as_float(u2.y << 16); p1.y += __uint_as_float(u2.y & 0xffff0000u);
        p0.x += __uint_as_float(u3.x << 16); p0.y += __uint_as_float(u3.x & 0xffff0000u);
        p1.x += __uint_as_float(u3.y << 16); p1.y += __uint_as_float(u3.y & 0xffff0000u);
    }
    for (; j < e; ++j) {
        const uint2 u = Xb[ci[j] * 64 + lane];
        p0.x += __uint_as_float(u.x << 16); p0.y += __uint_as_float(u.x & 0xffff0000u);
        p1.x += __uint_as_float(u.y << 16); p1.y += __uint_as_float(u.y & 0xffff0000u);
    }
    const uint32_t w0 = (uint32_t)f2b(p0.x * inv) | ((uint32_t)f2b(p0.y * inv) << 16);
    const uint32_t w1 = (uint32_t)f2b(p1.x * inv) | ((uint32_t)f2b(p1.y * inv) << 16);
    const uint64_t o = (uint64_t)w0 | ((uint64_t)w1 << 32);
    uint64_t* dst = (uint64_t*)(M + ((size_t)bag * NNODES + node) * DENC) + lane;
    __builtin_nontemporal_store(o, dst);
}

// ---------------------------------------------------------------------------
// classifier (fp32): out[b] = relu(emb[b]@Wc1 + bc1) @ Wc2 + bc2
// ---------------------------------------------------------------------------
__global__ __launch_bounds__(128)
void classifier_kernel(const float* __restrict__ emb, const float* __restrict__ Wc1,
                       const float* __restrict__ bc1, const float* __restrict__ Wc2,
                       const float* __restrict__ bc2, float* __restrict__ out)
{
    const int b = blockIdx.x;
    const int t = threadIdx.x;  // 128
    __shared__ float se[DENC];
    se[t] = emb[b * DENC + t];
    se[128 + t] = emb[b * DENC + 128 + t];
    __syncthreads();
    float h = bc1[t];
    for (int k = 0; k < DENC; ++k) h = fmaf(se[k], Wc1[k * DFC + t], h);
    h = fmaxf(h, 0.f);
    __shared__ float s0[128], s1[128];
    s0[t] = h * Wc2[t * NCLS + 0];
    s1[t] = h * Wc2[t * NCLS + 1];
    __syncthreads();
    for (int off = 64; off > 0; off >>= 1) {
        if (t < off) { s0[t] += s0[t + off]; s1[t] += s1[t + off]; }
        __syncthreads();
    }
    if (t == 0) {
        out[b * NCLS + 0] = s0[0] + bc2[0];
        out[b * NCLS + 1] = s1[0] + bc2[1];
    }
}

// ---------------------------------------------------------------------------
extern "C" void kernel_launch(void* const* d_in, const int* in_sizes, int n_in,
                              void* d_out, int out_size, void* d_ws, size_t ws_size,
                              hipStream_t stream)
{
    const float* x    = (const float*)d_in[0];
    const int*   edges= (const int*)d_in[1];   // int32 on device
    const float* We   = (const float*)d_in[2];
    const float* be   = (const float*)d_in[3];
    const float* Wl1  = (const float*)d_in[4];
    const float* bl1  = (const float*)d_in[5];
    const float* Wr1  = (const float*)d_in[6];
    const float* Wl2  = (const float*)d_in[7];
    const float* bl2  = (const float*)d_in[8];
    const float* Wr2  = (const float*)d_in[9];
    // d_in[10..12] = Wlp, blp, Wrp: dead (softmax over 1 cluster == 1)
    const float* Wc1  = (const float*)d_in[13];
    const float* bc1  = (const float*)d_in[14];
    const float* Wc2  = (const float*)d_in[15];
    const float* bc2  = (const float*)d_in[16];
    float* out = (float*)d_out;

    auto rnd = [](size_t v) { return (v + 255) & ~(size_t)255; };
    char* p = (char*)d_ws;
    auto alloc = [&](size_t bytes) -> char* {
        char* r = p; p += rnd(bytes); return r;
    };
    ushort* xb    = (ushort*)alloc((size_t)NBAGS * NNODES * DIN * 2);
    ushort* H     = (ushort*)alloc((size_t)NBAGS * NNODES * DENC * 2);  // h, then mean2
    ushort* Mb    = (ushort*)alloc((size_t)NBAGS * NNODES * DENC * 2);  // mean1
    ushort* Gb    = (ushort*)alloc((size_t)NBAGS * NNODES * DENC * 2);  // g1
    ushort* Wet   = (ushort*)alloc((size_t)256 * DIN * 2);
    ushort* Wl1t  = (ushort*)alloc((size_t)256 * DENC * 2);
    ushort* Wr1t  = (ushort*)alloc((size_t)256 * DENC * 2);
    ushort* Wl2t  = (ushort*)alloc((size_t)256 * DENC * 2);
    ushort* Wr2t  = (ushort*)alloc((size_t)256 * DENC * 2);
    int*    rowptr= (int*)   alloc((size_t)NBAGS * (NNODES + 1) * 4);
    int*    cnt   = (int*)   alloc((size_t)NBAGS * NNODES * 4);
    int*    histG = (int*)   alloc((size_t)NBAGS * HB * NNODES * 4);   // 10.24 MB
    ushort* colidx= (ushort*)alloc((size_t)NBAGS * NEDGES * 2);
    float*  emb   = (float*) alloc((size_t)NBAGS * DENC * 4);

    // per-launch init (ws re-poisoned each call)
    (void)hipMemsetAsync(emb, 0, (size_t)NBAGS * DENC * 4, stream);

    // conversions
    cvt_bf16_kernel<<<NBAGS * 625, 256, 0, stream>>>(x, xb);
    wt_transpose_kernel<<<(256 * DIN + 255) / 256, 256, 0, stream>>>(We, Wet, DIN);
    wt_transpose_kernel<<<(256 * DENC + 255) / 256, 256, 0, stream>>>(Wl1, Wl1t, DENC);
    wt_transpose_kernel<<<(256 * DENC + 255) / 256, 256, 0, stream>>>(Wr1, Wr1t, DENC);
    wt_transpose_kernel<<<(256 * DENC + 255) / 256, 256, 0, stream>>>(Wl2, Wl2t, DENC);
    wt_transpose_kernel<<<(256 * DENC + 255) / 256, 256, 0, stream>>>(Wr2, Wr2t, DENC);

    // CSR build (atomic-free counting sort, parallel prefix phases)
    hist_kernel<<<NBAGS * HB, 256, 0, stream>>>(edges, histG);
    colsum_kernel<<<NBAGS * 20, 256, 0, stream>>>(histG, cnt);
    scan_kernel<<<NBAGS, 1024, 0, stream>>>(cnt, rowptr);
    place_kernel<<<NBAGS * HB, 256, 0, stream>>>(edges, histG, rowptr, colidx);

    const int gemm_grid = NBAGS * TPB * 2;     // 1280
    const int agg_grid  = 8 * (NNODES / 4);    // 8 bags per launch

    // encoder: H = relu(x @ We + be)
    gemm_bf16_kernel<false, true, false><<<gemm_grid, 256, 0, stream>>>(
        xb, Wet, nullptr, nullptr, be, H, nullptr, DIN);

    // layer 1: g1 = relu(mean1@Wl1 + h@Wr1 + bl1)
    agg_mean_kernel<<<agg_grid, 256, 0, stream>>>(H, rowptr, colidx, Mb, 0);
    agg_mean_kernel<<<agg_grid, 256, 0, stream>>>(H, rowptr, colidx, Mb, 8);
    gemm_bf16_kernel<true, true, false><<<gemm_grid, 256, 0, stream>>>(
        Mb, Wl1t, H, Wr1t, bl1, Gb, nullptr, DENC);

    // layer 2 fused with emb reduction: emb += relu(mean2@Wl2 + g1@Wr2 + bl2)
    agg_mean_kernel<<<agg_grid, 256, 0, stream>>>(Gb, rowptr, colidx, H, 0);
    agg_mean_kernel<<<agg_grid, 256, 0, stream>>>(Gb, rowptr, colidx, H, 8);
    gemm_bf16_kernel<true, true, true><<<gemm_grid, 256, 0, stream>>>(
        H, Wl2t, Gb, Wr2t, bl2, nullptr, emb, DENC);

    classifier_kernel<<<NBAGS, 128, 0, stream>>>(emb, Wc1, bc1, Wc2, bc2, out);
}

// Round 12
// 413.114 us; speedup vs baseline: 1.3953x; 1.2437x over previous
//
#include <hip/hip_runtime.h>
#include <hip/hip_bf16.h>
#include <cstdint>
#include <cstddef>

// Problem constants (from reference)
#define NBAGS  16
#define NNODES 5000
#define NEDGES 160000
#define DIN    128
#define DENC   256   // == D_GNN
#define DFC    128
#define NCLS   2

#define TPB 40       // row-tiles of 128 per bag (40*128 = 5120 >= 5000)
#define HB  32       // hist blocks per bag
#define HEPB (NEDGES / HB)   // 5000 edges per hist block
#define LDSP 40      // padded LDS row stride (ushort elems)

typedef __attribute__((ext_vector_type(8))) short short8;
typedef __attribute__((ext_vector_type(4))) float f32x4;
typedef unsigned int uint32x4 __attribute__((ext_vector_type(4)));

static __device__ __forceinline__ ushort f2b(float v) {
    __hip_bfloat16 b = __float2bfloat16(v);   // RNE
    return *reinterpret_cast<ushort*>(&b);
}

// ---------------------------------------------------------------------------
// bf16 MFMA GEMM body, bag-pinned: 16 bags x 40 row-tiles x 2 col-halves =
// 1280 blocks; bag = bx&15 -> XCD bag%8 (same mapping everywhere).
// C[5000 x 256] per bag = act( A1@W1t^T (+ A2@W2t^T) + bias ), bf16 out.
// REDUCE=true: column-sum relu() into emb[bag][col] (g2 never materialized).
// smem: 2 x 128 x LDSP ushorts = 20480 B (red[128] aliases it post-K-loop).
// ---------------------------------------------------------------------------
template<bool DUAL, bool RELU, bool REDUCE>
__device__ __forceinline__
void gemm_body(int bx, char* smem,
               const ushort* __restrict__ A1, const ushort* __restrict__ Wt1,
               const ushort* __restrict__ A2, const ushort* __restrict__ Wt2,
               const float* __restrict__ bias, ushort* __restrict__ C,
               float* __restrict__ emb, int K)
{
    ushort* As = (ushort*)smem;
    ushort* Bs = As + 128 * LDSP;

    const int bag  = bx & 15;
    const int rem  = bx >> 4;          // 0..79
    const int col  = rem & 1;
    const int tile = rem >> 1;         // 0..39
    const size_t bagRow0 = (size_t)bag * NNODES;
    const int rloc0 = tile * 128;
    const int n0 = col * 128;

    const int tid  = threadIdx.x;
    const int wave = tid >> 6;
    const int lane = tid & 63;
    const int quad = lane >> 4;
    const int l16  = lane & 15;
    const int wm   = (wave >> 1) * 64;
    const int wn   = (wave & 1) * 64;

    f32x4 acc[4][4];
#pragma unroll
    for (int i = 0; i < 4; ++i)
#pragma unroll
        for (int j = 0; j < 4; ++j)
#pragma unroll
            for (int r = 0; r < 4; ++r) acc[i][j][r] = 0.f;

    const int sr = tid >> 1;           // staging row 0..127
    const int sk = (tid & 1) * 16;

    const int npass = DUAL ? 2 : 1;
    for (int pass = 0; pass < npass; ++pass) {
        const ushort* __restrict__ A = (DUAL && pass) ? A2 : A1;
        const ushort* __restrict__ W = (DUAL && pass) ? Wt2 : Wt1;

        for (int k0 = 0; k0 < K; k0 += 32) {
            {
                uint4 v0 = make_uint4(0, 0, 0, 0), v1 = make_uint4(0, 0, 0, 0);
                const int rl = rloc0 + sr;
                if (rl < NNODES) {
                    const uint4* src = (const uint4*)(A + (bagRow0 + rl) * K + k0 + sk);
                    v0 = src[0]; v1 = src[1];
                }
                *(uint4*)&As[sr * LDSP + sk]     = v0;
                *(uint4*)&As[sr * LDSP + sk + 8] = v1;
            }
            {
                const uint4* src = (const uint4*)(W + (size_t)(n0 + sr) * K + k0 + sk);
                *(uint4*)&Bs[sr * LDSP + sk]     = src[0];
                *(uint4*)&Bs[sr * LDSP + sk + 8] = src[1];
            }
            __syncthreads();

            short8 af[4], bf[4];
#pragma unroll
            for (int t = 0; t < 4; ++t) {
                af[t] = *(const short8*)&As[(wm + t * 16 + l16) * LDSP + quad * 8];
                bf[t] = *(const short8*)&Bs[(wn + t * 16 + l16) * LDSP + quad * 8];
            }
#pragma unroll
            for (int tm = 0; tm < 4; ++tm)
#pragma unroll
                for (int tn = 0; tn < 4; ++tn)
                    acc[tm][tn] = __builtin_amdgcn_mfma_f32_16x16x32_bf16(
                        af[tm], bf[tn], acc[tm][tn], 0, 0, 0);
            __syncthreads();
        }
    }

    if (!REDUCE) {
        // epilogue: bias + relu, bf16 store. C/D: row = quad*4+reg, col = l16
#pragma unroll
        for (int tm = 0; tm < 4; ++tm) {
            const int rbase = rloc0 + wm + tm * 16 + quad * 4;
#pragma unroll
            for (int reg = 0; reg < 4; ++reg) {
                const int rl = rbase + reg;
                if (rl < NNODES) {
#pragma unroll
                    for (int tn = 0; tn < 4; ++tn) {
                        const int gcol = n0 + wn + tn * 16 + l16;
                        float v = acc[tm][tn][reg] + bias[gcol];
                        if (RELU) v = fmaxf(v, 0.f);
                        C[(bagRow0 + rl) * 256 + gcol] = f2b(v);
                    }
                }
            }
        }
    } else {
        // fused column-sum epilogue -> emb[bag] (single bag per block).
        // red aliases smem — safe: K-loop ended with __syncthreads.
        float* red = (float*)smem;
        if (tid < 128) red[tid] = 0.f;
        __syncthreads();
#pragma unroll
        for (int tn = 0; tn < 4; ++tn) {
            const int cl = wn + tn * 16 + l16;            // 0..127
            const float bv = bias[n0 + cl];
            float p = 0.f;
#pragma unroll
            for (int tm = 0; tm < 4; ++tm) {
#pragma unroll
                for (int reg = 0; reg < 4; ++reg) {
                    const int rl = rloc0 + wm + tm * 16 + quad * 4 + reg;
                    float v = acc[tm][tn][reg] + bv;
                    if (RELU) v = fmaxf(v, 0.f);
                    if (rl < NNODES) p += v;
                }
            }
            atomicAdd(&red[cl], p);
        }
        __syncthreads();
        if (tid < 128)
            atomicAdd(&emb[bag * DENC + n0 + tid], red[tid]);
    }
}

template<bool DUAL, bool RELU, bool REDUCE>
__global__ __launch_bounds__(256)
void gemm_bf16_kernel(const ushort* __restrict__ A1, const ushort* __restrict__ Wt1,
                      const ushort* __restrict__ A2, const ushort* __restrict__ Wt2,
                      const float* __restrict__ bias, ushort* __restrict__ C,
                      float* __restrict__ emb, int K)
{
    __shared__ __align__(16) char smem[2 * 128 * LDSP * 2];
    gemm_body<DUAL, RELU, REDUCE>(blockIdx.x, smem, A1, Wt1, A2, Wt2, bias, C, emb, K);
}

// ---------------------------------------------------------------------------
// place body (CSR fill): per (bag,blk): h[i] = rowptr[i] + rel[i] in LDS,
// pos = LDS-atomicAdd, scatter colidx u16. smem: 20000 B int[NNODES].
// ---------------------------------------------------------------------------
__device__ __forceinline__
void place_body(int pbx, char* smem, const int* __restrict__ edges,
                const int* __restrict__ histG, const int* __restrict__ rowptr,
                ushort* __restrict__ colidx)
{
    const int bag = pbx & 15;
    const int blk = pbx >> 4;
    int* h = (int*)smem;
    const int* __restrict__ rel = histG + ((size_t)bag * HB + blk) * NNODES;
    const int* __restrict__ rp  = rowptr + bag * (NNODES + 1);
    for (int i = threadIdx.x; i < NNODES; i += 256) h[i] = rp[i] + rel[i];
    __syncthreads();
    const int* __restrict__ eb = edges + (size_t)bag * 2 * NEDGES;
    ushort* __restrict__ co = colidx + (size_t)bag * NEDGES;
    const int e0 = blk * HEPB;
    for (int r = threadIdx.x; r < HEPB; r += 256) {
        const int s = __builtin_nontemporal_load(&eb[e0 + r]);
        const int d = __builtin_nontemporal_load(&eb[NEDGES + e0 + r]);
        const int pos = atomicAdd(&h[d], 1);     // LDS atomic, CU-local
        co[pos] = (ushort)s;
    }
}

// encoder gemm (1280 blocks) + place (512 blocks) fused — independent work,
// place hides under the gemm. LDS unioned at 20480 B.
__global__ __launch_bounds__(256)
void enc_place_kernel(const ushort* __restrict__ xb, const ushort* __restrict__ Wet,
                      const float* __restrict__ be, ushort* __restrict__ H,
                      const int* __restrict__ edges, const int* __restrict__ histG,
                      const int* __restrict__ rowptr, ushort* __restrict__ colidx)
{
    __shared__ __align__(16) char smem[2 * 128 * LDSP * 2];
    if (blockIdx.x < NBAGS * TPB * 2)
        gemm_body<false, true, false>(blockIdx.x, smem, xb, Wet, nullptr, nullptr,
                                      be, H, nullptr, DIN);
    else
        place_body(blockIdx.x - NBAGS * TPB * 2, smem, edges, histG, rowptr, colidx);
}

// ---------------------------------------------------------------------------
// prep: hist (512, first so it starts immediately) + cvt (10000) + weight
// transpose (128 + 4*256) fused — all independent.
// ---------------------------------------------------------------------------
#define HIST_B (NBAGS * HB)       // 512
#define CVT_B  (NBAGS * 625)      // 10000
#define WTE_B  128
#define WTW_B  1024
#define PREP_GRID (HIST_B + CVT_B + WTE_B + WTW_B)

__global__ __launch_bounds__(256)
void prep_kernel(const int* __restrict__ edges, int* __restrict__ histG,
                 const float* __restrict__ x, ushort* __restrict__ xb,
                 const float* __restrict__ We,  ushort* __restrict__ Wet,
                 const float* __restrict__ Wl1, ushort* __restrict__ Wl1t,
                 const float* __restrict__ Wr1, ushort* __restrict__ Wr1t,
                 const float* __restrict__ Wl2, ushort* __restrict__ Wl2t,
                 const float* __restrict__ Wr2, ushort* __restrict__ Wr2t)
{
    __shared__ int sh[NNODES];
    const int bx = blockIdx.x;
    if (bx < HIST_B) {
        // hist role: LDS histogram of 5000 dst -> histG[bag][blk][*]
        const int bag = bx & 15;
        const int blk = bx >> 4;
        for (int i = threadIdx.x; i < NNODES; i += 256) sh[i] = 0;
        __syncthreads();
        const int* __restrict__ dstp =
            edges + (size_t)bag * 2 * NEDGES + NEDGES + blk * HEPB;
        for (int r = threadIdx.x; r < HEPB; r += 256)
            atomicAdd(&sh[__builtin_nontemporal_load(&dstp[r])], 1);
        __syncthreads();
        int* __restrict__ out = histG + ((size_t)bag * HB + blk) * NNODES;
        for (int i = threadIdx.x; i < NNODES; i += 256) out[i] = sh[i];
    } else if (bx < HIST_B + CVT_B) {
        // cvt role: x fp32 -> bf16, bag-pinned
        const int cbx = bx - HIST_B;
        const int bag = cbx & 15;
        const int chunk = cbx >> 4;
        const size_t base = (size_t)bag * (NNODES * DIN / 4);
        const int i = chunk * 256 + threadIdx.x;
        const float4 v = ((const float4*)x)[base + i];
        ushort4 o;
        o.x = f2b(v.x); o.y = f2b(v.y); o.z = f2b(v.z); o.w = f2b(v.w);
        ((ushort4*)xb)[base + i] = o;
    } else if (bx < HIST_B + CVT_B + WTE_B) {
        // We transpose: Wt[n*K+k] = bf16(W[k*256+n]), K=DIN
        const int idx = (bx - HIST_B - CVT_B) * 256 + threadIdx.x;
        const int n = idx / DIN;
        const int k = idx - n * DIN;
        Wet[idx] = f2b(We[k * 256 + n]);
    } else {
        // Wl1/Wr1/Wl2/Wr2 transpose, K=DENC
        const int r = bx - HIST_B - CVT_B - WTE_B;
        const int which = r >> 8;            // 0..3
        const int idx = (r & 255) * 256 + threadIdx.x;
        const int n = idx >> 8;
        const int k = idx & 255;
        const float* W  = (which == 0) ? Wl1 : (which == 1) ? Wr1 : (which == 2) ? Wl2 : Wr2;
        ushort* Wt      = (which == 0) ? Wl1t : (which == 1) ? Wr1t : (which == 2) ? Wl2t : Wr2t;
        Wt[idx] = f2b(W[k * 256 + n]);
    }
}

// ---------------------------------------------------------------------------
// colsum: thread = node; walk the 32 block-counts coalesced, rewrite in place
// as node-relative exclusive prefixes, total -> cnt. grid 16*20.
// ---------------------------------------------------------------------------
__global__ __launch_bounds__(256)
void colsum_kernel(int* __restrict__ histG, int* __restrict__ cnt)
{
    const int bag = blockIdx.x & 15;
    const int chunk = blockIdx.x >> 4;
    const int node = chunk * 256 + threadIdx.x;
    if (node >= NNODES) return;
    int* __restrict__ hb = histG + (size_t)bag * HB * NNODES + node;
    int run = 0;
#pragma unroll 8
    for (int blk = 0; blk < HB; ++blk) {
        int* p = hb + blk * NNODES;
        const int v = *p;
        *p = run;                        // node-relative exclusive prefix
        run += v;
    }
    cnt[bag * NNODES + node] = run;      // node degree
}

__global__ __launch_bounds__(1024)
void scan_kernel(const int* __restrict__ cnt, int* __restrict__ rowptr)
{
    const int b = blockIdx.x;
    const int t = threadIdx.x;
    __shared__ int sh[1024];
    const int CH = 5;                    // 1024*5 >= 5000
    const int base = t * CH;
    int local[CH];
    int sum = 0;
#pragma unroll
    for (int i = 0; i < CH; ++i) {
        const int g = base + i;
        const int v = (g < NNODES) ? cnt[b * NNODES + g] : 0;
        local[i] = v; sum += v;
    }
    sh[t] = sum;
    __syncthreads();
    for (int off = 1; off < 1024; off <<= 1) {
        const int add = (t >= off) ? sh[t - off] : 0;
        __syncthreads();
        sh[t] += add;
        __syncthreads();
    }
    int run = sh[t] - sum;               // exclusive prefix over nodes
#pragma unroll
    for (int i = 0; i < CH; ++i) {
        const int g = base + i;
        if (g < NNODES) rowptr[b * (NNODES + 1) + g] = run;
        run += local[i];
    }
    if (t == 1023) rowptr[b * (NNODES + 1) + NNODES] = run;  // == NEDGES
}

// ---------------------------------------------------------------------------
// Mean aggregation (pull), bf16 in/out, fp32 accumulate.
// One wave per node, TWO rows per vmem: halves (lane>>5) take even/odd edges,
// 32 lanes x 16 B = one full feature row per half. Halves combined with
// __shfl_xor(32); half 0 packs + NT-stores uint32x4 (512 B/row).
// 2 batches of 8 bags (bag = base + bx&7): one bag per XCD -> gather source
// stays in its L2. Accumulators are float2 -> v_pk_add_f32.
// ---------------------------------------------------------------------------
__global__ __launch_bounds__(256)
void agg_mean_kernel(const ushort* __restrict__ X, const int* __restrict__ rowptr,
                     const ushort* __restrict__ colidx, ushort* __restrict__ M,
                     int batchBase)
{
    const int bx = blockIdx.x;
    const int bag = batchBase + (bx & 7);
    const int grp = bx >> 3;                  // 0..1249
    const int wave = threadIdx.x >> 6;
    const int lane = threadIdx.x & 63;
    const int half = lane >> 5;
    const int hl = lane & 31;
    const int node = grp * 4 + wave;

    const int* rp = rowptr + bag * (NNODES + 1);
    const int s = rp[node];
    const int e = rp[node + 1];
    const float inv = 1.0f / fmaxf((float)(e - s), 1.0f);
    const uint32x4* __restrict__ Xb = (const uint32x4*)(X + (size_t)bag * NNODES * DENC);
    const ushort* __restrict__ ci = colidx + (size_t)bag * NEDGES;

    float2 a0 = {0.f, 0.f}, a1 = {0.f, 0.f}, a2 = {0.f, 0.f}, a3 = {0.f, 0.f};

    int j = s;
    for (; j + 8 <= e; j += 8) {
        int idx[4];
#pragma unroll
        for (int t = 0; t < 4; ++t) idx[t] = ci[j + 2 * t + half];
        uint32x4 u[4];
#pragma unroll
        for (int t = 0; t < 4; ++t) u[t] = Xb[idx[t] * 32 + hl];
#pragma unroll
        for (int t = 0; t < 4; ++t) {
            a0.x += __uint_as_float(u[t].x << 16);
            a0.y += __uint_as_float(u[t].x & 0xffff0000u);
            a1.x += __uint_as_float(u[t].y << 16);
            a1.y += __uint_as_float(u[t].y & 0xffff0000u);
            a2.x += __uint_as_float(u[t].z << 16);
            a2.y += __uint_as_float(u[t].z & 0xffff0000u);
            a3.x += __uint_as_float(u[t].w << 16);
            a3.y += __uint_as_float(u[t].w & 0xffff0000u);
        }
    }
    for (; j < e; j += 2) {
        const int jj = j + half;
        uint32x4 u = {0u, 0u, 0u, 0u};
        if (jj < e) u = Xb[(int)ci[jj] * 32 + hl];
        a0.x += __uint_as_float(u.x << 16);
        a0.y += __uint_as_float(u.x & 0xffff0000u);
        a1.x += __uint_as_float(u.y << 16);
        a1.y += __uint_as_float(u.y & 0xffff0000u);
        a2.x += __uint_as_float(u.z << 16);
        a2.y += __uint_as_float(u.z & 0xffff0000u);
        a3.x += __uint_as_float(u.w << 16);
        a3.y += __uint_as_float(u.w & 0xffff0000u);
    }

    // combine halves (even-edge + odd-edge partials)
    a0.x += __shfl_xor(a0.x, 32); a0.y += __shfl_xor(a0.y, 32);
    a1.x += __shfl_xor(a1.x, 32); a1.y += __shfl_xor(a1.y, 32);
    a2.x += __shfl_xor(a2.x, 32); a2.y += __shfl_xor(a2.y, 32);
    a3.x += __shfl_xor(a3.x, 32); a3.y += __shfl_xor(a3.y, 32);

    if (half == 0) {
        uint32x4 o;
        o.x = (uint32_t)f2b(a0.x * inv) | ((uint32_t)f2b(a0.y * inv) << 16);
        o.y = (uint32_t)f2b(a1.x * inv) | ((uint32_t)f2b(a1.y * inv) << 16);
        o.z = (uint32_t)f2b(a2.x * inv) | ((uint32_t)f2b(a2.y * inv) << 16);
        o.w = (uint32_t)f2b(a3.x * inv) | ((uint32_t)f2b(a3.y * inv) << 16);
        uint32x4* dst = (uint32x4*)(M + ((size_t)bag * NNODES + node) * DENC) + hl;
        __builtin_nontemporal_store(o, dst);
    }
}

// ---------------------------------------------------------------------------
// classifier (fp32): out[b] = relu(emb[b]@Wc1 + bc1) @ Wc2 + bc2
// ---------------------------------------------------------------------------
__global__ __launch_bounds__(128)
void classifier_kernel(const float* __restrict__ emb, const float* __restrict__ Wc1,
                       const float* __restrict__ bc1, const float* __restrict__ Wc2,
                       const float* __restrict__ bc2, float* __restrict__ out)
{
    const int b = blockIdx.x;
    const int t = threadIdx.x;  // 128
    __shared__ float se[DENC];
    se[t] = emb[b * DENC + t];
    se[128 + t] = emb[b * DENC + 128 + t];
    __syncthreads();
    float h = bc1[t];
    for (int k = 0; k < DENC; ++k) h = fmaf(se[k], Wc1[k * DFC + t], h);
    h = fmaxf(h, 0.f);
    __shared__ float s0[128], s1[128];
    s0[t] = h * Wc2[t * NCLS + 0];
    s1[t] = h * Wc2[t * NCLS + 1];
    __syncthreads();
    for (int off = 64; off > 0; off >>= 1) {
        if (t < off) { s0[t] += s0[t + off]; s1[t] += s1[t + off]; }
        __syncthreads();
    }
    if (t == 0) {
        out[b * NCLS + 0] = s0[0] + bc2[0];
        out[b * NCLS + 1] = s1[0] + bc2[1];
    }
}

// ---------------------------------------------------------------------------
extern "C" void kernel_launch(void* const* d_in, const int* in_sizes, int n_in,
                              void* d_out, int out_size, void* d_ws, size_t ws_size,
                              hipStream_t stream)
{
    const float* x    = (const float*)d_in[0];
    const int*   edges= (const int*)d_in[1];   // int32 on device
    const float* We   = (const float*)d_in[2];
    const float* be   = (const float*)d_in[3];
    const float* Wl1  = (const float*)d_in[4];
    const float* bl1  = (const float*)d_in[5];
    const float* Wr1  = (const float*)d_in[6];
    const float* Wl2  = (const float*)d_in[7];
    const float* bl2  = (const float*)d_in[8];
    const float* Wr2  = (const float*)d_in[9];
    // d_in[10..12] = Wlp, blp, Wrp: dead (softmax over 1 cluster == 1)
    const float* Wc1  = (const float*)d_in[13];
    const float* bc1  = (const float*)d_in[14];
    const float* Wc2  = (const float*)d_in[15];
    const float* bc2  = (const float*)d_in[16];
    float* out = (float*)d_out;

    auto rnd = [](size_t v) { return (v + 255) & ~(size_t)255; };
    char* p = (char*)d_ws;
    auto alloc = [&](size_t bytes) -> char* {
        char* r = p; p += rnd(bytes); return r;
    };
    ushort* xb    = (ushort*)alloc((size_t)NBAGS * NNODES * DIN * 2);
    ushort* H     = (ushort*)alloc((size_t)NBAGS * NNODES * DENC * 2);  // h, then mean2
    ushort* Mb    = (ushort*)alloc((size_t)NBAGS * NNODES * DENC * 2);  // mean1
    ushort* Gb    = (ushort*)alloc((size_t)NBAGS * NNODES * DENC * 2);  // g1
    ushort* Wet   = (ushort*)alloc((size_t)256 * DIN * 2);
    ushort* Wl1t  = (ushort*)alloc((size_t)256 * DENC * 2);
    ushort* Wr1t  = (ushort*)alloc((size_t)256 * DENC * 2);
    ushort* Wl2t  = (ushort*)alloc((size_t)256 * DENC * 2);
    ushort* Wr2t  = (ushort*)alloc((size_t)256 * DENC * 2);
    int*    rowptr= (int*)   alloc((size_t)NBAGS * (NNODES + 1) * 4);
    int*    cnt   = (int*)   alloc((size_t)NBAGS * NNODES * 4);
    int*    histG = (int*)   alloc((size_t)NBAGS * HB * NNODES * 4);   // 10.24 MB
    ushort* colidx= (ushort*)alloc((size_t)NBAGS * NEDGES * 2);
    float*  emb   = (float*) alloc((size_t)NBAGS * DENC * 4);

    // per-launch init (ws re-poisoned each call)
    (void)hipMemsetAsync(emb, 0, (size_t)NBAGS * DENC * 4, stream);

    // fused prep: hist + x-convert + weight transposes (independent work)
    prep_kernel<<<PREP_GRID, 256, 0, stream>>>(
        edges, histG, x, xb, We, Wet, Wl1, Wl1t, Wr1, Wr1t, Wl2, Wl2t, Wr2, Wr2t);

    // CSR prefix phases
    colsum_kernel<<<NBAGS * 20, 256, 0, stream>>>(histG, cnt);
    scan_kernel<<<NBAGS, 1024, 0, stream>>>(cnt, rowptr);

    // encoder gemm + CSR place fused (independent; place hides under gemm)
    enc_place_kernel<<<NBAGS * TPB * 2 + HIST_B, 256, 0, stream>>>(
        xb, Wet, be, H, edges, histG, rowptr, colidx);

    const int gemm_grid = NBAGS * TPB * 2;     // 1280
    const int agg_grid  = 8 * (NNODES / 4);    // 8 bags per launch

    // layer 1: g1 = relu(mean1@Wl1 + h@Wr1 + bl1)
    agg_mean_kernel<<<agg_grid, 256, 0, stream>>>(H, rowptr, colidx, Mb, 0);
    agg_mean_kernel<<<agg_grid, 256, 0, stream>>>(H, rowptr, colidx, Mb, 8);
    gemm_bf16_kernel<true, true, false><<<gemm_grid, 256, 0, stream>>>(
        Mb, Wl1t, H, Wr1t, bl1, Gb, nullptr, DENC);

    // layer 2 fused with emb reduction: emb += relu(mean2@Wl2 + g1@Wr2 + bl2)
    agg_mean_kernel<<<agg_grid, 256, 0, stream>>>(Gb, rowptr, colidx, H, 0);
    agg_mean_kernel<<<agg_grid, 256, 0, stream>>>(Gb, rowptr, colidx, H, 8);
    gemm_bf16_kernel<true, true, true><<<gemm_grid, 256, 0, stream>>>(
        H, Wl2t, Gb, Wr2t, bl2, nullptr, emb, DENC);

    classifier_kernel<<<NBAGS, 128, 0, stream>>>(emb, Wc1, bc1, Wc2, bc2, out);
}

// Round 13
// 412.023 us; speedup vs baseline: 1.3990x; 1.0026x over previous
//
#include <hip/hip_runtime.h>
#include <hip/hip_bf16.h>
#include <cstdint>
#include <cstddef>

// Problem constants (from reference)
#define NBAGS  16
#define NNODES 5000
#define NEDGES 160000
#define DIN    128
#define DENC   256   // == D_GNN
#define DFC    128
#define NCLS   2

#define TPB 40       // row-tiles of 128 per bag (40*128 = 5120 >= 5000)
#define HB  32       // hist blocks per bag
#define HEPB (NEDGES / HB)   // 5000 edges per hist block

typedef __attribute__((ext_vector_type(8))) short short8;
typedef __attribute__((ext_vector_type(4))) float f32x4;
typedef unsigned int uint32x4 __attribute__((ext_vector_type(4)));

static __device__ __forceinline__ ushort f2b(float v) {
    __hip_bfloat16 b = __float2bfloat16(v);   // RNE
    return *reinterpret_cast<ushort*>(&b);
}

// ---------------------------------------------------------------------------
// bf16 MFMA GEMM body, bag-pinned: 16 bags x 40 row-tiles x 2 col-halves =
// 1280 blocks; bag = bx&15 -> XCD bag%8 (same mapping everywhere).
// C[5000 x 256] per bag = act( A1@W1t^T (+ A2@W2t^T) + bias ), bf16 out.
// REDUCE=true: column-sum relu() into emb[bag][col] (g2 never materialized).
//
// LDS: CHUNKED-K layout — plane c (16 B of k) stored contiguously over rows:
//   addr(c,row) = (c*128 + row)*8 ushorts. Fragment-read bank base =
//   (row*4)%32: 256 dwords land exactly 8/bank (HW minimum) -> conflict-free
//   (old [row][k] stride-40 layout cost 5.2M SQ_LDS_BANK_CONFLICT/dispatch).
//   All addresses stay 16 B aligned; 8 KB per matrix, 16 KB total.
// ---------------------------------------------------------------------------
template<bool DUAL, bool RELU, bool REDUCE>
__device__ __forceinline__
void gemm_body(int bx, char* smem,
               const ushort* __restrict__ A1, const ushort* __restrict__ Wt1,
               const ushort* __restrict__ A2, const ushort* __restrict__ Wt2,
               const float* __restrict__ bias, ushort* __restrict__ C,
               float* __restrict__ emb, int K)
{
    ushort* As = (ushort*)smem;          // 4096 ushorts
    ushort* Bs = As + 4096;

    const int bag  = bx & 15;
    const int rem  = bx >> 4;          // 0..79
    const int col  = rem & 1;
    const int tile = rem >> 1;         // 0..39
    const size_t bagRow0 = (size_t)bag * NNODES;
    const int rloc0 = tile * 128;
    const int n0 = col * 128;

    const int tid  = threadIdx.x;
    const int wave = tid >> 6;
    const int lane = tid & 63;
    const int quad = lane >> 4;
    const int l16  = lane & 15;
    const int wm   = (wave >> 1) * 64;
    const int wn   = (wave & 1) * 64;

    f32x4 acc[4][4];
#pragma unroll
    for (int i = 0; i < 4; ++i)
#pragma unroll
        for (int j = 0; j < 4; ++j)
#pragma unroll
            for (int r = 0; r < 4; ++r) acc[i][j][r] = 0.f;

    const int sr = tid >> 1;           // staging row 0..127
    const int sc = (tid & 1) * 2;      // staging chunk 0 or 2
    const int sk = sc * 8;             // k elem offset 0 or 16

    const int npass = DUAL ? 2 : 1;
    for (int pass = 0; pass < npass; ++pass) {
        const ushort* __restrict__ A = (DUAL && pass) ? A2 : A1;
        const ushort* __restrict__ W = (DUAL && pass) ? Wt2 : Wt1;

        for (int k0 = 0; k0 < K; k0 += 32) {
            {
                uint4 v0 = make_uint4(0, 0, 0, 0), v1 = make_uint4(0, 0, 0, 0);
                const int rl = rloc0 + sr;
                if (rl < NNODES) {
                    const uint4* src = (const uint4*)(A + (bagRow0 + rl) * K + k0 + sk);
                    v0 = src[0]; v1 = src[1];
                }
                *(uint4*)&As[(sc * 128 + sr) * 8]       = v0;
                *(uint4*)&As[((sc + 1) * 128 + sr) * 8] = v1;
            }
            {
                const uint4* src = (const uint4*)(W + (size_t)(n0 + sr) * K + k0 + sk);
                *(uint4*)&Bs[(sc * 128 + sr) * 8]       = src[0];
                *(uint4*)&Bs[((sc + 1) * 128 + sr) * 8] = src[1];
            }
            __syncthreads();

            short8 af[4], bf[4];
#pragma unroll
            for (int t = 0; t < 4; ++t) {
                af[t] = *(const short8*)&As[(quad * 128 + wm + t * 16 + l16) * 8];
                bf[t] = *(const short8*)&Bs[(quad * 128 + wn + t * 16 + l16) * 8];
            }
#pragma unroll
            for (int tm = 0; tm < 4; ++tm)
#pragma unroll
                for (int tn = 0; tn < 4; ++tn)
                    acc[tm][tn] = __builtin_amdgcn_mfma_f32_16x16x32_bf16(
                        af[tm], bf[tn], acc[tm][tn], 0, 0, 0);
            __syncthreads();
        }
    }

    if (!REDUCE) {
        // epilogue: bias + relu, bf16 store. C/D: row = quad*4+reg, col = l16
#pragma unroll
        for (int tm = 0; tm < 4; ++tm) {
            const int rbase = rloc0 + wm + tm * 16 + quad * 4;
#pragma unroll
            for (int reg = 0; reg < 4; ++reg) {
                const int rl = rbase + reg;
                if (rl < NNODES) {
#pragma unroll
                    for (int tn = 0; tn < 4; ++tn) {
                        const int gcol = n0 + wn + tn * 16 + l16;
                        float v = acc[tm][tn][reg] + bias[gcol];
                        if (RELU) v = fmaxf(v, 0.f);
                        C[(bagRow0 + rl) * 256 + gcol] = f2b(v);
                    }
                }
            }
        }
    } else {
        // fused column-sum epilogue -> emb[bag] (single bag per block).
        // red aliases smem — safe: K-loop ended with __syncthreads.
        float* red = (float*)smem;
        if (tid < 128) red[tid] = 0.f;
        __syncthreads();
#pragma unroll
        for (int tn = 0; tn < 4; ++tn) {
            const int cl = wn + tn * 16 + l16;            // 0..127
            const float bv = bias[n0 + cl];
            float p = 0.f;
#pragma unroll
            for (int tm = 0; tm < 4; ++tm) {
#pragma unroll
                for (int reg = 0; reg < 4; ++reg) {
                    const int rl = rloc0 + wm + tm * 16 + quad * 4 + reg;
                    float v = acc[tm][tn][reg] + bv;
                    if (RELU) v = fmaxf(v, 0.f);
                    if (rl < NNODES) p += v;
                }
            }
            atomicAdd(&red[cl], p);
        }
        __syncthreads();
        if (tid < 128)
            atomicAdd(&emb[bag * DENC + n0 + tid], red[tid]);
    }
}

template<bool DUAL, bool RELU, bool REDUCE>
__global__ __launch_bounds__(256)
void gemm_bf16_kernel(const ushort* __restrict__ A1, const ushort* __restrict__ Wt1,
                      const ushort* __restrict__ A2, const ushort* __restrict__ Wt2,
                      const float* __restrict__ bias, ushort* __restrict__ C,
                      float* __restrict__ emb, int K)
{
    __shared__ __align__(16) char smem[16384];
    gemm_body<DUAL, RELU, REDUCE>(blockIdx.x, smem, A1, Wt1, A2, Wt2, bias, C, emb, K);
}

// ---------------------------------------------------------------------------
// place body (CSR fill): per (bag,blk): h[i] = rowptr[i] + rel[i] in LDS,
// pos = LDS-atomicAdd, scatter colidx u16. smem: 20000 B int[NNODES].
// ---------------------------------------------------------------------------
__device__ __forceinline__
void place_body(int pbx, char* smem, const int* __restrict__ edges,
                const int* __restrict__ histG, const int* __restrict__ rowptr,
                ushort* __restrict__ colidx)
{
    const int bag = pbx & 15;
    const int blk = pbx >> 4;
    int* h = (int*)smem;
    const int* __restrict__ rel = histG + ((size_t)bag * HB + blk) * NNODES;
    const int* __restrict__ rp  = rowptr + bag * (NNODES + 1);
    for (int i = threadIdx.x; i < NNODES; i += 256) h[i] = rp[i] + rel[i];
    __syncthreads();
    const int* __restrict__ eb = edges + (size_t)bag * 2 * NEDGES;
    ushort* __restrict__ co = colidx + (size_t)bag * NEDGES;
    const int e0 = blk * HEPB;
    for (int r = threadIdx.x; r < HEPB; r += 256) {
        const int s = __builtin_nontemporal_load(&eb[e0 + r]);
        const int d = __builtin_nontemporal_load(&eb[NEDGES + e0 + r]);
        const int pos = atomicAdd(&h[d], 1);     // LDS atomic, CU-local
        co[pos] = (ushort)s;
    }
}

// encoder gemm (1280 blocks) + place (512 blocks) fused — independent work,
// place hides under the gemm. LDS unioned at 20480 B (place needs 20000).
__global__ __launch_bounds__(256)
void enc_place_kernel(const ushort* __restrict__ xb, const ushort* __restrict__ Wet,
                      const float* __restrict__ be, ushort* __restrict__ H,
                      const int* __restrict__ edges, const int* __restrict__ histG,
                      const int* __restrict__ rowptr, ushort* __restrict__ colidx)
{
    __shared__ __align__(16) char smem[20480];
    if (blockIdx.x < NBAGS * TPB * 2)
        gemm_body<false, true, false>(blockIdx.x, smem, xb, Wet, nullptr, nullptr,
                                      be, H, nullptr, DIN);
    else
        place_body(blockIdx.x - NBAGS * TPB * 2, smem, edges, histG, rowptr, colidx);
}

// ---------------------------------------------------------------------------
// prep: hist (512, first so it starts immediately) + cvt (10000) + weight
// transpose (128 + 4*256) fused — all independent.
// ---------------------------------------------------------------------------
#define HIST_B (NBAGS * HB)       // 512
#define CVT_B  (NBAGS * 625)      // 10000
#define WTE_B  128
#define WTW_B  1024
#define PREP_GRID (HIST_B + CVT_B + WTE_B + WTW_B)

__global__ __launch_bounds__(256)
void prep_kernel(const int* __restrict__ edges, int* __restrict__ histG,
                 const float* __restrict__ x, ushort* __restrict__ xb,
                 const float* __restrict__ We,  ushort* __restrict__ Wet,
                 const float* __restrict__ Wl1, ushort* __restrict__ Wl1t,
                 const float* __restrict__ Wr1, ushort* __restrict__ Wr1t,
                 const float* __restrict__ Wl2, ushort* __restrict__ Wl2t,
                 const float* __restrict__ Wr2, ushort* __restrict__ Wr2t)
{
    __shared__ int sh[NNODES];
    const int bx = blockIdx.x;
    if (bx < HIST_B) {
        // hist role: LDS histogram of 5000 dst -> histG[bag][blk][*]
        const int bag = bx & 15;
        const int blk = bx >> 4;
        for (int i = threadIdx.x; i < NNODES; i += 256) sh[i] = 0;
        __syncthreads();
        const int* __restrict__ dstp =
            edges + (size_t)bag * 2 * NEDGES + NEDGES + blk * HEPB;
        for (int r = threadIdx.x; r < HEPB; r += 256)
            atomicAdd(&sh[__builtin_nontemporal_load(&dstp[r])], 1);
        __syncthreads();
        int* __restrict__ out = histG + ((size_t)bag * HB + blk) * NNODES;
        for (int i = threadIdx.x; i < NNODES; i += 256) out[i] = sh[i];
    } else if (bx < HIST_B + CVT_B) {
        // cvt role: x fp32 -> bf16, bag-pinned
        const int cbx = bx - HIST_B;
        const int bag = cbx & 15;
        const int chunk = cbx >> 4;
        const size_t base = (size_t)bag * (NNODES * DIN / 4);
        const int i = chunk * 256 + threadIdx.x;
        const float4 v = ((const float4*)x)[base + i];
        ushort4 o;
        o.x = f2b(v.x); o.y = f2b(v.y); o.z = f2b(v.z); o.w = f2b(v.w);
        ((ushort4*)xb)[base + i] = o;
    } else if (bx < HIST_B + CVT_B + WTE_B) {
        // We transpose: Wt[n*K+k] = bf16(W[k*256+n]), K=DIN
        const int idx = (bx - HIST_B - CVT_B) * 256 + threadIdx.x;
        const int n = idx / DIN;
        const int k = idx - n * DIN;
        Wet[idx] = f2b(We[k * 256 + n]);
    } else {
        // Wl1/Wr1/Wl2/Wr2 transpose, K=DENC
        const int r = bx - HIST_B - CVT_B - WTE_B;
        const int which = r >> 8;            // 0..3
        const int idx = (r & 255) * 256 + threadIdx.x;
        const int n = idx >> 8;
        const int k = idx & 255;
        const float* W  = (which == 0) ? Wl1 : (which == 1) ? Wr1 : (which == 2) ? Wl2 : Wr2;
        ushort* Wt      = (which == 0) ? Wl1t : (which == 1) ? Wr1t : (which == 2) ? Wl2t : Wr2t;
        Wt[idx] = f2b(W[k * 256 + n]);
    }
}

// ---------------------------------------------------------------------------
// colsum: thread = node; walk the 32 block-counts coalesced, rewrite in place
// as node-relative exclusive prefixes, total -> cnt. grid 16*20.
// ---------------------------------------------------------------------------
__global__ __launch_bounds__(256)
void colsum_kernel(int* __restrict__ histG, int* __restrict__ cnt)
{
    const int bag = blockIdx.x & 15;
    const int chunk = blockIdx.x >> 4;
    const int node = chunk * 256 + threadIdx.x;
    if (node >= NNODES) return;
    int* __restrict__ hb = histG + (size_t)bag * HB * NNODES + node;
    int run = 0;
#pragma unroll 8
    for (int blk = 0; blk < HB; ++blk) {
        int* p = hb + blk * NNODES;
        const int v = *p;
        *p = run;                        // node-relative exclusive prefix
        run += v;
    }
    cnt[bag * NNODES + node] = run;      // node degree
}

__global__ __launch_bounds__(1024)
void scan_kernel(const int* __restrict__ cnt, int* __restrict__ rowptr)
{
    const int b = blockIdx.x;
    const int t = threadIdx.x;
    __shared__ int sh[1024];
    const int CH = 5;                    // 1024*5 >= 5000
    const int base = t * CH;
    int local[CH];
    int sum = 0;
#pragma unroll
    for (int i = 0; i < CH; ++i) {
        const int g = base + i;
        const int v = (g < NNODES) ? cnt[b * NNODES + g] : 0;
        local[i] = v; sum += v;
    }
    sh[t] = sum;
    __syncthreads();
    for (int off = 1; off < 1024; off <<= 1) {
        const int add = (t >= off) ? sh[t - off] : 0;
        __syncthreads();
        sh[t] += add;
        __syncthreads();
    }
    int run = sh[t] - sum;               // exclusive prefix over nodes
#pragma unroll
    for (int i = 0; i < CH; ++i) {
        const int g = base + i;
        if (g < NNODES) rowptr[b * (NNODES + 1) + g] = run;
        run += local[i];
    }
    if (t == 1023) rowptr[b * (NNODES + 1) + NNODES] = run;  // == NEDGES
}

// ---------------------------------------------------------------------------
// Mean aggregation (pull), bf16 in/out, fp32 accumulate.
// One wave per node, TWO rows per vmem: halves (lane>>5) take even/odd edges,
// 32 lanes x 16 B = one full feature row per half. Halves combined with
// __shfl_xor(32); half 0 packs + NT-stores uint32x4 (512 B/row).
// 2 batches of 8 bags (bag = base + bx&7): one bag per XCD -> gather source
// stays in its L2. Accumulators are float2 -> v_pk_add_f32.
// ---------------------------------------------------------------------------
__global__ __launch_bounds__(256)
void agg_mean_kernel(const ushort* __restrict__ X, const int* __restrict__ rowptr,
                     const ushort* __restrict__ colidx, ushort* __restrict__ M,
                     int batchBase)
{
    const int bx = blockIdx.x;
    const int bag = batchBase + (bx & 7);
    const int grp = bx >> 3;                  // 0..1249
    const int wave = threadIdx.x >> 6;
    const int lane = threadIdx.x & 63;
    const int half = lane >> 5;
    const int hl = lane & 31;
    const int node = grp * 4 + wave;

    const int* rp = rowptr + bag * (NNODES + 1);
    const int s = rp[node];
    const int e = rp[node + 1];
    const float inv = 1.0f / fmaxf((float)(e - s), 1.0f);
    const uint32x4* __restrict__ Xb = (const uint32x4*)(X + (size_t)bag * NNODES * DENC);
    const ushort* __restrict__ ci = colidx + (size_t)bag * NEDGES;

    float2 a0 = {0.f, 0.f}, a1 = {0.f, 0.f}, a2 = {0.f, 0.f}, a3 = {0.f, 0.f};

    int j = s;
    for (; j + 8 <= e; j += 8) {
        int idx[4];
#pragma unroll
        for (int t = 0; t < 4; ++t) idx[t] = ci[j + 2 * t + half];
        uint32x4 u[4];
#pragma unroll
        for (int t = 0; t < 4; ++t) u[t] = Xb[idx[t] * 32 + hl];
#pragma unroll
        for (int t = 0; t < 4; ++t) {
            a0.x += __uint_as_float(u[t].x << 16);
            a0.y += __uint_as_float(u[t].x & 0xffff0000u);
            a1.x += __uint_as_float(u[t].y << 16);
            a1.y += __uint_as_float(u[t].y & 0xffff0000u);
            a2.x += __uint_as_float(u[t].z << 16);
            a2.y += __uint_as_float(u[t].z & 0xffff0000u);
            a3.x += __uint_as_float(u[t].w << 16);
            a3.y += __uint_as_float(u[t].w & 0xffff0000u);
        }
    }
    for (; j < e; j += 2) {
        const int jj = j + half;
        uint32x4 u = {0u, 0u, 0u, 0u};
        if (jj < e) u = Xb[(int)ci[jj] * 32 + hl];
        a0.x += __uint_as_float(u.x << 16);
        a0.y += __uint_as_float(u.x & 0xffff0000u);
        a1.x += __uint_as_float(u.y << 16);
        a1.y += __uint_as_float(u.y & 0xffff0000u);
        a2.x += __uint_as_float(u.z << 16);
        a2.y += __uint_as_float(u.z & 0xffff0000u);
        a3.x += __uint_as_float(u.w << 16);
        a3.y += __uint_as_float(u.w & 0xffff0000u);
    }

    // combine halves (even-edge + odd-edge partials)
    a0.x += __shfl_xor(a0.x, 32); a0.y += __shfl_xor(a0.y, 32);
    a1.x += __shfl_xor(a1.x, 32); a1.y += __shfl_xor(a1.y, 32);
    a2.x += __shfl_xor(a2.x, 32); a2.y += __shfl_xor(a2.y, 32);
    a3.x += __shfl_xor(a3.x, 32); a3.y += __shfl_xor(a3.y, 32);

    if (half == 0) {
        uint32x4 o;
        o.x = (uint32_t)f2b(a0.x * inv) | ((uint32_t)f2b(a0.y * inv) << 16);
        o.y = (uint32_t)f2b(a1.x * inv) | ((uint32_t)f2b(a1.y * inv) << 16);
        o.z = (uint32_t)f2b(a2.x * inv) | ((uint32_t)f2b(a2.y * inv) << 16);
        o.w = (uint32_t)f2b(a3.x * inv) | ((uint32_t)f2b(a3.y * inv) << 16);
        uint32x4* dst = (uint32x4*)(M + ((size_t)bag * NNODES + node) * DENC) + hl;
        __builtin_nontemporal_store(o, dst);
    }
}

// ---------------------------------------------------------------------------
// classifier (fp32): out[b] = relu(emb[b]@Wc1 + bc1) @ Wc2 + bc2
// ---------------------------------------------------------------------------
__global__ __launch_bounds__(128)
void classifier_kernel(const float* __restrict__ emb, const float* __restrict__ Wc1,
                       const float* __restrict__ bc1, const float* __restrict__ Wc2,
                       const float* __restrict__ bc2, float* __restrict__ out)
{
    const int b = blockIdx.x;
    const int t = threadIdx.x;  // 128
    __shared__ float se[DENC];
    se[t] = emb[b * DENC + t];
    se[128 + t] = emb[b * DENC + 128 + t];
    __syncthreads();
    float h = bc1[t];
    for (int k = 0; k < DENC; ++k) h = fmaf(se[k], Wc1[k * DFC + t], h);
    h = fmaxf(h, 0.f);
    __shared__ float s0[128], s1[128];
    s0[t] = h * Wc2[t * NCLS + 0];
    s1[t] = h * Wc2[t * NCLS + 1];
    __syncthreads();
    for (int off = 64; off > 0; off >>= 1) {
        if (t < off) { s0[t] += s0[t + off]; s1[t] += s1[t + off]; }
        __syncthreads();
    }
    if (t == 0) {
        out[b * NCLS + 0] = s0[0] + bc2[0];
        out[b * NCLS + 1] = s1[0] + bc2[1];
    }
}

// ---------------------------------------------------------------------------
extern "C" void kernel_launch(void* const* d_in, const int* in_sizes, int n_in,
                              void* d_out, int out_size, void* d_ws, size_t ws_size,
                              hipStream_t stream)
{
    const float* x    = (const float*)d_in[0];
    const int*   edges= (const int*)d_in[1];   // int32 on device
    const float* We   = (const float*)d_in[2];
    const float* be   = (const float*)d_in[3];
    const float* Wl1  = (const float*)d_in[4];
    const float* bl1  = (const float*)d_in[5];
    const float* Wr1  = (const float*)d_in[6];
    const float* Wl2  = (const float*)d_in[7];
    const float* bl2  = (const float*)d_in[8];
    const float* Wr2  = (const float*)d_in[9];
    // d_in[10..12] = Wlp, blp, Wrp: dead (softmax over 1 cluster == 1)
    const float* Wc1  = (const float*)d_in[13];
    const float* bc1  = (const float*)d_in[14];
    const float* Wc2  = (const float*)d_in[15];
    const float* bc2  = (const float*)d_in[16];
    float* out = (float*)d_out;

    auto rnd = [](size_t v) { return (v + 255) & ~(size_t)255; };
    char* p = (char*)d_ws;
    auto alloc = [&](size_t bytes) -> char* {
        char* r = p; p += rnd(bytes); return r;
    };
    ushort* xb    = (ushort*)alloc((size_t)NBAGS * NNODES * DIN * 2);
    ushort* H     = (ushort*)alloc((size_t)NBAGS * NNODES * DENC * 2);  // h, then mean2
    ushort* Mb    = (ushort*)alloc((size_t)NBAGS * NNODES * DENC * 2);  // mean1
    ushort* Gb    = (ushort*)alloc((size_t)NBAGS * NNODES * DENC * 2);  // g1
    ushort* Wet   = (ushort*)alloc((size_t)256 * DIN * 2);
    ushort* Wl1t  = (ushort*)alloc((size_t)256 * DENC * 2);
    ushort* Wr1t  = (ushort*)alloc((size_t)256 * DENC * 2);
    ushort* Wl2t  = (ushort*)alloc((size_t)256 * DENC * 2);
    ushort* Wr2t  = (ushort*)alloc((size_t)256 * DENC * 2);
    int*    rowptr= (int*)   alloc((size_t)NBAGS * (NNODES + 1) * 4);
    int*    cnt   = (int*)   alloc((size_t)NBAGS * NNODES * 4);
    int*    histG = (int*)   alloc((size_t)NBAGS * HB * NNODES * 4);   // 10.24 MB
    ushort* colidx= (ushort*)alloc((size_t)NBAGS * NEDGES * 2);
    float*  emb   = (float*) alloc((size_t)NBAGS * DENC * 4);

    // per-launch init (ws re-poisoned each call)
    (void)hipMemsetAsync(emb, 0, (size_t)NBAGS * DENC * 4, stream);

    // fused prep: hist + x-convert + weight transposes (independent work)
    prep_kernel<<<PREP_GRID, 256, 0, stream>>>(
        edges, histG, x, xb, We, Wet, Wl1, Wl1t, Wr1, Wr1t, Wl2, Wl2t, Wr2, Wr2t);

    // CSR prefix phases
    colsum_kernel<<<NBAGS * 20, 256, 0, stream>>>(histG, cnt);
    scan_kernel<<<NBAGS, 1024, 0, stream>>>(cnt, rowptr);

    // encoder gemm + CSR place fused (independent; place hides under gemm)
    enc_place_kernel<<<NBAGS * TPB * 2 + HIST_B, 256, 0, stream>>>(
        xb, Wet, be, H, edges, histG, rowptr, colidx);

    const int gemm_grid = NBAGS * TPB * 2;     // 1280
    const int agg_grid  = 8 * (NNODES / 4);    // 8 bags per launch

    // layer 1: g1 = relu(mean1@Wl1 + h@Wr1 + bl1)
    agg_mean_kernel<<<agg_grid, 256, 0, stream>>>(H, rowptr, colidx, Mb, 0);
    agg_mean_kernel<<<agg_grid, 256, 0, stream>>>(H, rowptr, colidx, Mb, 8);
    gemm_bf16_kernel<true, true, false><<<gemm_grid, 256, 0, stream>>>(
        Mb, Wl1t, H, Wr1t, bl1, Gb, nullptr, DENC);

    // layer 2 fused with emb reduction: emb += relu(mean2@Wl2 + g1@Wr2 + bl2)
    agg_mean_kernel<<<agg_grid, 256, 0, stream>>>(Gb, rowptr, colidx, H, 0);
    agg_mean_kernel<<<agg_grid, 256, 0, stream>>>(Gb, rowptr, colidx, H, 8);
    gemm_bf16_kernel<true, true, true><<<gemm_grid, 256, 0, stream>>>(
        H, Wl2t, Gb, Wr2t, bl2, nullptr, emb, DENC);

    classifier_kernel<<<NBAGS, 128, 0, stream>>>(emb, Wc1, bc1, Wc2, bc2, out);
}